// Round 3
// baseline (201.898 us; speedup 1.0000x reference)
//
#include <hip/hip_runtime.h>
#include <hip/hip_bf16.h>

#define DD   4096   // hidden dim
#define NE   8      // experts
#define NR   16     // lora rank
#define NTOK 8192   // B*S
#define NDO  4096   // output dim
// SCALING = 16/16 = 1.0

typedef __attribute__((ext_vector_type(8))) __bf16 bf16x8;
typedef __attribute__((ext_vector_type(4))) float  f32x4;

__device__ __forceinline__ bf16x8 to_bf16x8(float4 a, float4 b) {
    bf16x8 r;
    r[0] = (__bf16)a.x; r[1] = (__bf16)a.y; r[2] = (__bf16)a.z; r[3] = (__bf16)a.w;
    r[4] = (__bf16)b.x; r[5] = (__bf16)b.y; r[6] = (__bf16)b.z; r[7] = (__bf16)b.w;
    return r;
}

// ---------------- k1: routing (f64 logits) + expert binning ----------------
// 2048 blocks x 256 threads. Block = 4 tokens; wave wv covers D-slice
// [wv*1024, wv*1024+1024). Direct loads (no LDS staging), split-D for occupancy.
__global__ __launch_bounds__(256) void k_route(const float* __restrict__ x,
                                               const float* __restrict__ rw,
                                               float* __restrict__ w_arr,
                                               int*   __restrict__ token_list,
                                               int*   __restrict__ count) {
    const int wv   = threadIdx.x >> 6;        // 0..3: D-slice
    const int lane = threadIdx.x & 63;
    const int t0   = blockIdx.x * 4;
    const float* xp = x + (size_t)t0 * DD;
    const int dbase = wv * 1024;

    double acc[4][NE];
    #pragma unroll
    for (int t = 0; t < 4; t++)
        #pragma unroll
        for (int e = 0; e < NE; e++) acc[t][e] = 0.0;

    #pragma unroll
    for (int i = 0; i < 4; i++) {
        const int d4 = dbase + (i * 64 + lane) * 4;
        double xd[4][4];
        #pragma unroll
        for (int t = 0; t < 4; t++) {
            const float4 xv = *(const float4*)(xp + (size_t)t * DD + d4);
            xd[t][0] = xv.x; xd[t][1] = xv.y; xd[t][2] = xv.z; xd[t][3] = xv.w;
        }
        #pragma unroll
        for (int e = 0; e < NE; e++) {
            const float4 wv4 = *(const float4*)(rw + (size_t)e * DD + d4);
            const double w0 = wv4.x, w1 = wv4.y, w2 = wv4.z, w3 = wv4.w;
            #pragma unroll
            for (int t = 0; t < 4; t++) {
                acc[t][e] = fma(xd[t][0], w0, acc[t][e]);
                acc[t][e] = fma(xd[t][1], w1, acc[t][e]);
                acc[t][e] = fma(xd[t][2], w2, acc[t][e]);
                acc[t][e] = fma(xd[t][3], w3, acc[t][e]);
            }
        }
    }

    // 64-lane butterfly (f64): every lane ends with the full slice sums
    #pragma unroll
    for (int off = 32; off > 0; off >>= 1) {
        #pragma unroll
        for (int t = 0; t < 4; t++)
            #pragma unroll
            for (int e = 0; e < NE; e++)
                acc[t][e] += __shfl_xor(acc[t][e], off, 64);
    }

    // combine the 4 D-slices in LDS (f64, exact)
    __shared__ double red[4][4][NE];          // [wave][token][expert]
    if (lane < 32) red[wv][lane >> 3][lane & 7] = acc[lane >> 3][lane & 7];
    __syncthreads();
    if (threadIdx.x < 32) {
        const int t = threadIdx.x >> 3, e = threadIdx.x & 7;
        red[0][t][e] = red[0][t][e] + red[1][t][e] + red[2][t][e] + red[3][t][e];
    }
    __syncthreads();
    if (threadIdx.x < 4) {
        const int t = threadIdx.x;
        double best = red[0][t][0]; int be = 0;
        #pragma unroll
        for (int e = 1; e < NE; e++)
            if (red[0][t][e] > best) { best = red[0][t][e]; be = e; }
        const int tok = t0 + t;
        w_arr[tok] = (float)best;
        const int pos = atomicAdd(&count[be], 1);
        token_list[be * NTOK + pos] = tok;
    }
}

// ---------------- k2: wh[tok][r] = w * (x . A[e]^T)  (bf16 out) ----------------
// grid 8*512 WGs of 512 threads (8 waves, K=512 slice each). One WG = 16-token tile.
__global__ __launch_bounds__(512) void k_h(const float* __restrict__ x,
                                           const float* __restrict__ Am,
                                           const float* __restrict__ w_arr,
                                           const int*   __restrict__ token_list,
                                           const int*   __restrict__ count,
                                           __hip_bfloat16* __restrict__ wh) {
    const int e    = blockIdx.x >> 9;
    const int g    = blockIdx.x & 511;
    const int cnt  = count[e];
    const int base = g * 16;
    if (base >= cnt) return;

    const int wv   = threadIdx.x >> 6;        // 0..7
    const int lane = threadIdx.x & 63;
    const int m    = lane & 15;               // token row / A-row (r)
    const int half = lane >> 4;

    const int  idx   = base + m;
    const bool valid = idx < cnt;
    const int  tok   = valid ? token_list[e * NTOK + idx] : 0;
    const float* xrow = x  + (size_t)tok * DD;
    const float* arow = Am + ((size_t)e * NR + m) * DD;

    f32x4 acc = {0.f, 0.f, 0.f, 0.f};
    const int kbase = wv * 512;
    #pragma unroll 4
    for (int ks = 0; ks < 16; ks++) {
        const int k0 = kbase + ks * 32 + half * 8;
        const float4 xa = *(const float4*)(xrow + k0);
        const float4 xb = *(const float4*)(xrow + k0 + 4);
        const float4 aa = *(const float4*)(arow + k0);
        const float4 ab = *(const float4*)(arow + k0 + 4);
        const bf16x8 af = to_bf16x8(xa, xb);
        const bf16x8 bf = to_bf16x8(aa, ab);
        acc = __builtin_amdgcn_mfma_f32_16x16x32_bf16(af, bf, acc, 0, 0, 0);
    }

    // C layout: row = (lane>>4)*4 + reg (token), col = lane&15 (r)
    __shared__ float lds[8][16][20];
    #pragma unroll
    for (int r = 0; r < 4; r++) lds[wv][half * 4 + r][m] = acc[r];
    __syncthreads();

    if (threadIdx.x < 256) {
        const int t = threadIdx.x >> 4;
        const int r = threadIdx.x & 15;
        const int i2 = base + t;
        if (i2 < cnt) {
            float s = 0.f;
            #pragma unroll
            for (int w = 0; w < 8; w++) s += lds[w][t][r];
            const int tk = token_list[e * NTOK + i2];
            wh[(size_t)tk * NR + r] = (__hip_bfloat16)(s * w_arr[tk]);
        }
    }
}

// ---------------- k3: out = wh . Bw[e]^T ----------------
// grid 8*512*4 WGs of 256 threads. block = 16-token tile x 1024-output chunk;
// wave = 256 outputs (16 o-tiles).
__global__ __launch_bounds__(256) void k_out(const float* __restrict__ Bw,
                                             const __hip_bfloat16* __restrict__ wh,
                                             const int*   __restrict__ token_list,
                                             const int*   __restrict__ count,
                                             float* __restrict__ out) {
    const int bx    = blockIdx.x;
    const int chunk = bx & 3;
    const int slot  = (bx >> 2) & 511;
    const int e     = bx >> 11;
    const int cnt   = count[e];
    const int base  = slot * 16;
    if (base >= cnt) return;

    const int wv   = threadIdx.x >> 6;        // 0..3
    const int lane = threadIdx.x & 63;
    const int m    = lane & 15;
    const int half = lane >> 4;

    const int  idx   = base + m;
    const bool valid = idx < cnt;
    const int  tok   = valid ? token_list[e * NTOK + idx] : 0;

    // a2 frag: wh[m-token][k], k = half*8+j for half<2, zero-padded K=32
    bf16x8 a2;
    if (half < 2 && valid) {
        a2 = *(const bf16x8*)(wh + (size_t)tok * NR + half * 8);
    } else {
        #pragma unroll
        for (int j = 0; j < 8; j++) a2[j] = (__bf16)0.0f;
    }

    int trow[4]; bool vrow[4];
    #pragma unroll
    for (int r = 0; r < 4; r++) {
        const int ir = base + half * 4 + r;
        vrow[r] = ir < cnt;
        trow[r] = vrow[r] ? token_list[e * NTOK + ir] : 0;
    }

    const float* bwe = Bw + (size_t)e * NDO * NR;
    const int h2 = (half < 2) ? half : 0;
    const f32x4 zero4 = {0.f, 0.f, 0.f, 0.f};
    const int ob0 = chunk * 1024 + wv * 256;

    #pragma unroll 4
    for (int ot = 0; ot < 16; ot++) {
        const int obase = ob0 + ot * 16;
        const float* bp = bwe + (size_t)(obase + m) * NR + h2 * 8;
        const float4 p = *(const float4*)(bp);
        const float4 q = *(const float4*)(bp + 4);
        bf16x8 b2 = to_bf16x8(p, q);
        if (half >= 2) {
            #pragma unroll
            for (int j = 0; j < 8; j++) b2[j] = (__bf16)0.0f;
        }
        const f32x4 d = __builtin_amdgcn_mfma_f32_16x16x32_bf16(a2, b2, zero4, 0, 0, 0);
        #pragma unroll
        for (int r = 0; r < 4; r++) {
            if (vrow[r]) out[(size_t)trow[r] * NDO + obase + m] = d[r];
        }
    }
}

// ---------------- launcher ----------------
extern "C" void kernel_launch(void* const* d_in, const int* in_sizes, int n_in,
                              void* d_out, int out_size, void* d_ws, size_t ws_size,
                              hipStream_t stream) {
    const float* x  = (const float*)d_in[0];
    const float* rw = (const float*)d_in[1];
    const float* Am = (const float*)d_in[2];
    const float* Bw = (const float*)d_in[3];
    float* out = (float*)d_out;

    char* ws = (char*)d_ws;
    int*   count      = (int*)ws;                           // 8 ints
    float* w_arr      = (float*)(ws + 512);                 // 8192 f32
    int*   token_list = (int*)(ws + 65536);                 // 8*8192 ints
    __hip_bfloat16* wh = (__hip_bfloat16*)(ws + 65536 + NE * NTOK * 4); // 8192*16 bf16

    hipMemsetAsync(count, 0, NE * sizeof(int), stream);
    hipLaunchKernelGGL(k_route, dim3(2048),  dim3(256), 0, stream, x, rw, w_arr, token_list, count);
    hipLaunchKernelGGL(k_h,     dim3(4096),  dim3(512), 0, stream, x, Am, w_arr, token_list, count, wh);
    hipLaunchKernelGGL(k_out,   dim3(16384), dim3(256), 0, stream, Bw, wh, token_list, count, out);
}

// Round 4
// 182.169 us; speedup vs baseline: 1.1083x; 1.1083x over previous
//
#include <hip/hip_runtime.h>
#include <hip/hip_bf16.h>

#define DD   4096   // hidden dim
#define NE   8      // experts
#define NR   16     // lora rank
#define NTOK 8192   // B*S
#define NDO  4096   // output dim
// SCALING = 16/16 = 1.0

typedef __attribute__((ext_vector_type(8))) __bf16 bf16x8;
typedef __attribute__((ext_vector_type(4))) float  f32x4;

__device__ __forceinline__ bf16x8 to_bf16x8(float4 a, float4 b) {
    bf16x8 r;
    r[0] = (__bf16)a.x; r[1] = (__bf16)a.y; r[2] = (__bf16)a.z; r[3] = (__bf16)a.w;
    r[4] = (__bf16)b.x; r[5] = (__bf16)b.y; r[6] = (__bf16)b.z; r[7] = (__bf16)b.w;
    return r;
}

// ---------------- k1: routing (f64 logits) + expert binning ----------------
// 1024 blocks x 256 threads (4 waves). Wave = 2 tokens, FULL D.
// acc = f64[2][8] = 32 VGPR; no LDS, no barriers; butterfly reduce only.
// launch_bounds(256,4): VGPR cap 128 -> no spill (r3 had 131MB scratch WRITE).
__global__ __launch_bounds__(256, 4) void k_route(const float* __restrict__ x,
                                                  const float* __restrict__ rw,
                                                  float* __restrict__ w_arr,
                                                  int*   __restrict__ token_list,
                                                  int*   __restrict__ count) {
    const int wv   = threadIdx.x >> 6;
    const int lane = threadIdx.x & 63;
    const int t0   = blockIdx.x * 8 + wv * 2;
    const float* xp0 = x + (size_t)t0 * DD;
    const float* xp1 = xp0 + DD;

    double acc0[NE], acc1[NE];
    #pragma unroll
    for (int e = 0; e < NE; e++) { acc0[e] = 0.0; acc1[e] = 0.0; }

    #pragma unroll 2
    for (int i = 0; i < 16; i++) {
        const int d4 = (i * 64 + lane) * 4;
        const float4 xv0 = *(const float4*)(xp0 + d4);
        const float4 xv1 = *(const float4*)(xp1 + d4);
        const double x00 = xv0.x, x01 = xv0.y, x02 = xv0.z, x03 = xv0.w;
        const double x10 = xv1.x, x11 = xv1.y, x12 = xv1.z, x13 = xv1.w;
        #pragma unroll
        for (int e = 0; e < NE; e++) {
            const float4 wv4 = *(const float4*)(rw + (size_t)e * DD + d4);
            const double w0 = wv4.x, w1 = wv4.y, w2 = wv4.z, w3 = wv4.w;
            acc0[e] = fma(x00, w0, acc0[e]);
            acc0[e] = fma(x01, w1, acc0[e]);
            acc0[e] = fma(x02, w2, acc0[e]);
            acc0[e] = fma(x03, w3, acc0[e]);
            acc1[e] = fma(x10, w0, acc1[e]);
            acc1[e] = fma(x11, w1, acc1[e]);
            acc1[e] = fma(x12, w2, acc1[e]);
            acc1[e] = fma(x13, w3, acc1[e]);
        }
    }

    // 64-lane butterfly (f64): every lane ends with complete sums
    #pragma unroll
    for (int off = 32; off > 0; off >>= 1) {
        #pragma unroll
        for (int e = 0; e < NE; e++) {
            acc0[e] += __shfl_xor(acc0[e], off, 64);
            acc1[e] += __shfl_xor(acc1[e], off, 64);
        }
    }

    // statically-indexed argmax per lane (no runtime-indexed array -> no scratch)
    if (lane == 0) {
        double best = acc0[0]; int be = 0;
        #pragma unroll
        for (int e = 1; e < NE; e++) if (acc0[e] > best) { best = acc0[e]; be = e; }
        w_arr[t0] = (float)best;
        const int pos = atomicAdd(&count[be], 1);
        token_list[be * NTOK + pos] = t0;
    } else if (lane == 1) {
        double best = acc1[0]; int be = 0;
        #pragma unroll
        for (int e = 1; e < NE; e++) if (acc1[e] > best) { best = acc1[e]; be = e; }
        w_arr[t0 + 1] = (float)best;
        const int pos = atomicAdd(&count[be], 1);
        token_list[be * NTOK + pos] = t0 + 1;
    }
}

// ---------------- k2: wh[tok][r] = w * (x . A[e]^T)  (bf16 out) ----------------
// grid 8*512 WGs of 512 threads (8 waves, K=512 slice each). One WG = 16-token tile.
__global__ __launch_bounds__(512) void k_h(const float* __restrict__ x,
                                           const float* __restrict__ Am,
                                           const float* __restrict__ w_arr,
                                           const int*   __restrict__ token_list,
                                           const int*   __restrict__ count,
                                           __hip_bfloat16* __restrict__ wh) {
    const int e    = blockIdx.x >> 9;
    const int g    = blockIdx.x & 511;
    const int cnt  = count[e];
    const int base = g * 16;
    if (base >= cnt) return;

    const int wv   = threadIdx.x >> 6;        // 0..7
    const int lane = threadIdx.x & 63;
    const int m    = lane & 15;               // token row / A-row (r)
    const int half = lane >> 4;

    const int  idx   = base + m;
    const bool valid = idx < cnt;
    const int  tok   = valid ? token_list[e * NTOK + idx] : 0;
    const float* xrow = x  + (size_t)tok * DD;
    const float* arow = Am + ((size_t)e * NR + m) * DD;

    f32x4 acc = {0.f, 0.f, 0.f, 0.f};
    const int kbase = wv * 512;
    #pragma unroll 4
    for (int ks = 0; ks < 16; ks++) {
        const int k0 = kbase + ks * 32 + half * 8;
        const float4 xa = *(const float4*)(xrow + k0);
        const float4 xb = *(const float4*)(xrow + k0 + 4);
        const float4 aa = *(const float4*)(arow + k0);
        const float4 ab = *(const float4*)(arow + k0 + 4);
        const bf16x8 af = to_bf16x8(xa, xb);
        const bf16x8 bf = to_bf16x8(aa, ab);
        acc = __builtin_amdgcn_mfma_f32_16x16x32_bf16(af, bf, acc, 0, 0, 0);
    }

    // C layout: row = (lane>>4)*4 + reg (token), col = lane&15 (r)
    __shared__ float lds[8][16][20];
    #pragma unroll
    for (int r = 0; r < 4; r++) lds[wv][half * 4 + r][m] = acc[r];
    __syncthreads();

    if (threadIdx.x < 256) {
        const int t = threadIdx.x >> 4;
        const int r = threadIdx.x & 15;
        const int i2 = base + t;
        if (i2 < cnt) {
            float s = 0.f;
            #pragma unroll
            for (int w = 0; w < 8; w++) s += lds[w][t][r];
            const int tk = token_list[e * NTOK + i2];
            wh[(size_t)tk * NR + r] = (__hip_bfloat16)(s * w_arr[tk]);
        }
    }
}

// ---------------- k3: out = wh . Bw[e]^T ----------------
// grid 8*512*4 WGs of 256 threads. block = 16-token tile x 1024-output chunk;
// wave = 256 outputs (16 o-tiles).
__global__ __launch_bounds__(256) void k_out(const float* __restrict__ Bw,
                                             const __hip_bfloat16* __restrict__ wh,
                                             const int*   __restrict__ token_list,
                                             const int*   __restrict__ count,
                                             float* __restrict__ out) {
    const int bx    = blockIdx.x;
    const int chunk = bx & 3;
    const int slot  = (bx >> 2) & 511;
    const int e     = bx >> 11;
    const int cnt   = count[e];
    const int base  = slot * 16;
    if (base >= cnt) return;

    const int wv   = threadIdx.x >> 6;        // 0..3
    const int lane = threadIdx.x & 63;
    const int m    = lane & 15;
    const int half = lane >> 4;

    const int  idx   = base + m;
    const bool valid = idx < cnt;
    const int  tok   = valid ? token_list[e * NTOK + idx] : 0;

    // a2 frag: wh[m-token][k], k = half*8+j for half<2, zero-padded K=32
    bf16x8 a2;
    if (half < 2 && valid) {
        a2 = *(const bf16x8*)(wh + (size_t)tok * NR + half * 8);
    } else {
        #pragma unroll
        for (int j = 0; j < 8; j++) a2[j] = (__bf16)0.0f;
    }

    int trow[4]; bool vrow[4];
    #pragma unroll
    for (int r = 0; r < 4; r++) {
        const int ir = base + half * 4 + r;
        vrow[r] = ir < cnt;
        trow[r] = vrow[r] ? token_list[e * NTOK + ir] : 0;
    }

    const float* bwe = Bw + (size_t)e * NDO * NR;
    const int h2 = (half < 2) ? half : 0;
    const f32x4 zero4 = {0.f, 0.f, 0.f, 0.f};
    const int ob0 = chunk * 1024 + wv * 256;

    #pragma unroll 4
    for (int ot = 0; ot < 16; ot++) {
        const int obase = ob0 + ot * 16;
        const float* bp = bwe + (size_t)(obase + m) * NR + h2 * 8;
        const float4 p = *(const float4*)(bp);
        const float4 q = *(const float4*)(bp + 4);
        bf16x8 b2 = to_bf16x8(p, q);
        if (half >= 2) {
            #pragma unroll
            for (int j = 0; j < 8; j++) b2[j] = (__bf16)0.0f;
        }
        const f32x4 d = __builtin_amdgcn_mfma_f32_16x16x32_bf16(a2, b2, zero4, 0, 0, 0);
        #pragma unroll
        for (int r = 0; r < 4; r++) {
            if (vrow[r]) out[(size_t)trow[r] * NDO + obase + m] = d[r];
        }
    }
}

// ---------------- launcher ----------------
extern "C" void kernel_launch(void* const* d_in, const int* in_sizes, int n_in,
                              void* d_out, int out_size, void* d_ws, size_t ws_size,
                              hipStream_t stream) {
    const float* x  = (const float*)d_in[0];
    const float* rw = (const float*)d_in[1];
    const float* Am = (const float*)d_in[2];
    const float* Bw = (const float*)d_in[3];
    float* out = (float*)d_out;

    char* ws = (char*)d_ws;
    int*   count      = (int*)ws;                           // 8 ints
    float* w_arr      = (float*)(ws + 512);                 // 8192 f32
    int*   token_list = (int*)(ws + 65536);                 // 8*8192 ints
    __hip_bfloat16* wh = (__hip_bfloat16*)(ws + 65536 + NE * NTOK * 4); // 8192*16 bf16

    hipMemsetAsync(count, 0, NE * sizeof(int), stream);
    hipLaunchKernelGGL(k_route, dim3(1024),  dim3(256), 0, stream, x, rw, w_arr, token_list, count);
    hipLaunchKernelGGL(k_h,     dim3(4096),  dim3(512), 0, stream, x, Am, w_arr, token_list, count, wh);
    hipLaunchKernelGGL(k_out,   dim3(16384), dim3(256), 0, stream, Bw, wh, token_list, count, out);
}